// Round 1
// baseline (1240.513 us; speedup 1.0000x reference)
//
#include <hip/hip_runtime.h>
#include <math.h>

// Problem constants (fixed by setup_inputs): T=2, B=32, Nt=196(14x14), D=768,
// heads=12, hd=64, H_s=W_s=96, N_s=9217 (incl. CLS at index 0).
// search_key = 32*12*9217*64 f32 = 906 MB -> attn kernel is the HBM stream.
#define TT 2
#define BB 32
#define DD 768
#define HEADS 12
#define HD 64
#define HT 14
#define WT 14
#define HS 96
#define WS 96
#define NS (HS*WS)        // 9216
#define NSK (NS+1)        // 9217
#define SMW (WS-WT+1)     // 83
#define SMH (HS-HT+1)     // 83

#define CHUNKS 12
#define CROWS (NS / CHUNKS)   // 768 rows per attn block
#define CITERS (CROWS / 16)   // 48 iterations (16 rows per iteration)

// ---------------------------------------------------------------------------
// Kernel 1: per-(t,b) masked proto pooling. grid = (3 d-chunks, T, B), 256 thr.
// protos[t][b][d] = sum_{masked cells} patches[t,b,cell,d] / (count + 1e-6)
// Coalesced: lane d reads consecutive floats for each masked cell.
// ---------------------------------------------------------------------------
__global__ __launch_bounds__(256) void proto_kernel(
    const float* __restrict__ patches, const float* __restrict__ annos,
    float* __restrict__ protos) {
  const int dc = blockIdx.x, t = blockIdx.y, b = blockIdx.z;
  const int d = dc * 256 + threadIdx.x;

  const float* an = annos + (t * BB + b) * 4;
  const float ax = an[0], ay = an[1], aw = an[2], ah = an[3];
  const int x1 = (int)floorf(ax * (float)WT);
  const int y1 = (int)floorf(ay * (float)HT);
  const int x2 = (int)floorf((ax + aw) * (float)WT);
  const int y2 = (int)floorf((ay + ah) * (float)HT);
  const int cx2 = min(x2, WT), cy2 = min(y2, HT);
  const int cw = max(cx2 - x1, 0), ch = max(cy2 - y1, 0);
  const float count = (float)(cw * ch);

  float s = 0.f;
  const float* base = patches + ((size_t)(t * BB + b)) * (HT*WT) * DD + d;
  for (int r = y1; r < cy2; ++r)
    for (int c = x1; c < cx2; ++c)
      s += base[(r * WT + c) * DD];

  protos[(size_t)(t * BB + b) * DD + d] = s / (count + 1e-6f);
}

// ---------------------------------------------------------------------------
// Kernel 2 (v2): head-split streaming attention.
// grid = (CHUNKS=12, HEADS=12, B=32) = 4608 blocks, 256 thr.
// Each block owns one (b, h, 768-row chunk): a single CONTIGUOUS 192 KB
// stream (f4 index i*256 + tid per iteration -> 4 KB/block-iteration).
// Only 1 float4 of proto per thread (vs 48 VGPRs before) -> max occupancy,
// deep load pipeline. 16-lane shfl_xor reduces each row's dot immediately;
// per-head partials go to track_h scratch (written exactly once, no init).
// ---------------------------------------------------------------------------
__global__ __launch_bounds__(256, 8) void attn_kernel(
    const float* __restrict__ sk, const float* __restrict__ protos,
    float* __restrict__ track_h) {
  const int chunk = blockIdx.x, h = blockIdx.y, b = blockIdx.z;
  const int tid = threadIdx.x;
  const int lane16 = tid & 15;       // d-slice within head (float4 slot)
  const int grp = tid >> 4;          // row-within-16 subgroup

  // proto for this (b,h): average over T=2 templates, 4 floats per lane16.
  const float4* p0 = (const float4*)(protos + (size_t)b * DD + h * HD);
  const float4* p1 = (const float4*)(protos + (size_t)(BB + b) * DD + h * HD);
  const float4 a = p0[lane16], c = p1[lane16];
  const float4 pr = make_float4(0.5f * (a.x + c.x), 0.5f * (a.y + c.y),
                                0.5f * (a.z + c.z), 0.5f * (a.w + c.w));

  const int row0 = chunk * CROWS;
  const float4* base =
      (const float4*)(sk + ((size_t)(b * HEADS + h) * NSK + 1 + row0) * HD);
  float* outb = track_h + (size_t)(b * HEADS + h) * NS + row0;

  #pragma unroll 8
  for (int i = 0; i < CITERS; ++i) {
    // wave reads f4 indices i*256 + tid -> 1 KB contiguous per wave instr,
    // 4 KB contiguous per block-iteration, sequential across i.
    const float4 v = base[i * 256 + tid];
    float r = v.x * pr.x + v.y * pr.y + v.z * pr.z + v.w * pr.w;
    r += __shfl_xor(r, 1, 64);
    r += __shfl_xor(r, 2, 64);
    r += __shfl_xor(r, 4, 64);
    r += __shfl_xor(r, 8, 64);
    if (lane16 == 0) outb[i * 16 + grp] = r;   // per-head partial dot
  }
}

// ---------------------------------------------------------------------------
// Kernel 3: head-sum + blur + softmax + integral image + box-argmax.
// One block per b. LDS: Q[96*96] (head-summed track) + P[97*97] + red.
// ---------------------------------------------------------------------------
__device__ __forceinline__ int reflect96(int p) {
  return p < 0 ? -p : (p > 95 ? 190 - p : p);
}

__global__ __launch_bounds__(256) void post_kernel(
    const float* __restrict__ track_h, float* __restrict__ out) {
  __shared__ float P[97 * 97];
  __shared__ float Q[96 * 96];
  __shared__ float red[256];
  __shared__ int redi[256];
  const int b = blockIdx.x, tid = threadIdx.x;

  // Gaussian weights, sigma=1.1 (matches ref: exp(-r^2/(2*1.21)) normalized)
  const float e2 = expf(-4.0f / (2.0f * 1.1f * 1.1f));
  const float e1 = expf(-1.0f / (2.0f * 1.1f * 1.1f));
  const float wsum = 2.f * e2 + 2.f * e1 + 1.f;
  const float w0 = e2 / wsum, w1 = e1 / wsum, w2 = 1.f / wsum;

  // head-sum: track[b][n] = (1/96) * sum_h track_h[b][h][n]
  // (1/96 = head-mean 1/12 * hd^-0.5 = 1/8). track_h is L3-resident (14 MB).
  const float* trh = track_h + (size_t)b * HEADS * NS;
  for (int i = tid; i < NS; i += 256) {
    float s = 0.f;
    #pragma unroll
    for (int h = 0; h < HEADS; ++h) s += trh[h * NS + i];
    Q[i] = s * (1.0f / 96.0f);
  }
  __syncthreads();

  // vertical blur (reflect) from LDS Q
  for (int i = tid; i < NS; i += 256) {
    const int r = i / WS, c = i % WS;
    float acc = w2 * Q[r * WS + c];
    acc += w1 * (Q[reflect96(r - 1) * WS + c] + Q[reflect96(r + 1) * WS + c]);
    acc += w0 * (Q[reflect96(r - 2) * WS + c] + Q[reflect96(r + 2) * WS + c]);
    P[r * 97 + c] = acc;
  }
  __syncthreads();

  // horizontal blur -> registers (36 pixels/thread)
  float vals[36];
  #pragma unroll
  for (int k = 0; k < 36; ++k) {
    const int i = tid + k * 256;
    const int r = i / WS, c = i % WS;
    float acc = w2 * P[r * 97 + c];
    acc += w1 * (P[r * 97 + reflect96(c - 1)] + P[r * 97 + reflect96(c + 1)]);
    acc += w0 * (P[r * 97 + reflect96(c - 2)] + P[r * 97 + reflect96(c + 2)]);
    vals[k] = acc;
  }
  __syncthreads();

  // softmax over all 9216
  float lm = -1e30f;
  #pragma unroll
  for (int k = 0; k < 36; ++k) lm = fmaxf(lm, vals[k]);
  red[tid] = lm; __syncthreads();
  for (int s = 128; s > 0; s >>= 1) {
    if (tid < s) red[tid] = fmaxf(red[tid], red[tid + s]);
    __syncthreads();
  }
  const float m = red[0]; __syncthreads();

  float ls = 0.f;
  #pragma unroll
  for (int k = 0; k < 36; ++k) { vals[k] = expf(vals[k] - m); ls += vals[k]; }
  red[tid] = ls; __syncthreads();
  for (int s = 128; s > 0; s >>= 1) {
    if (tid < s) red[tid] += red[tid + s];
    __syncthreads();
  }
  const float inv = 1.0f / red[0]; __syncthreads();

  // write prob to out; store shifted into P interior for the integral image
  float* prob_out = out + 5 * BB + (size_t)b * NS;
  #pragma unroll
  for (int k = 0; k < 36; ++k) {
    const int i = tid + k * 256;
    const int r = i / WS, c = i % WS;
    const float p = vals[k] * inv;
    prob_out[i] = p;
    P[(r + 1) * 97 + (c + 1)] = p;
  }
  for (int i = tid; i < 97; i += 256) { P[i] = 0.f; P[i * 97] = 0.f; }
  __syncthreads();

  // in-place column prefix (cols 1..96) — loads independent, adds pipelined
  if (tid < 96) {
    const int c = tid + 1;
    float run = P[97 + c];
    for (int r = 2; r < 97; ++r) { run += P[r * 97 + c]; P[r * 97 + c] = run; }
  }
  __syncthreads();
  // in-place row prefix (rows 1..96)
  if (tid < 96) {
    const int r = tid + 1;
    float run = 0.f;
    for (int c = 1; c < 97; ++c) { run += P[r * 97 + c]; P[r * 97 + c] = run; }
  }
  __syncthreads();

  // argmax over 83x83 box sums (first-occurrence tie-break like jnp.argmax)
  float bv = -1e30f; int bi = 0x7fffffff;
  for (int i = tid; i < SMH * SMW; i += 256) {
    const int y = i / SMW, x = i % SMW;
    const float v = P[(y + HT) * 97 + (x + WT)] - P[y * 97 + (x + WT)]
                  - P[(y + HT) * 97 + x] + P[y * 97 + x];
    if (v > bv || (v == bv && i < bi)) { bv = v; bi = i; }
  }
  red[tid] = bv; redi[tid] = bi; __syncthreads();
  for (int s = 128; s > 0; s >>= 1) {
    if (tid < s) {
      const float ov = red[tid + s]; const int oi = redi[tid + s];
      if (ov > red[tid] || (ov == red[tid] && oi < redi[tid])) {
        red[tid] = ov; redi[tid] = oi;
      }
    }
    __syncthreads();
  }

  if (tid == 0) {
    const int idx = redi[0];
    out[0 * BB + b] = (float)(idx % SMW);   // best_x
    out[1 * BB + b] = (float)(idx / SMW);   // best_y
    out[2 * BB + b] = (float)WT;            // win_w
    out[3 * BB + b] = (float)HT;            // win_h
    out[4 * BB + b] = red[0];               // confidence
  }
}

// ---------------------------------------------------------------------------
extern "C" void kernel_launch(void* const* d_in, const int* in_sizes, int n_in,
                              void* d_out, int out_size, void* d_ws, size_t ws_size,
                              hipStream_t stream) {
  (void)in_sizes; (void)n_in; (void)out_size; (void)ws_size;
  const float* patches = (const float*)d_in[0];
  const float* annos   = (const float*)d_in[1];
  const float* sk      = (const float*)d_in[2];
  float* ws = (float*)d_ws;
  float* protos  = ws;                          // TT*BB*DD = 49152 floats
  float* track_h = ws + (size_t)TT * BB * DD;   // BB*HEADS*NS = 3538944 floats
  float* out = (float*)d_out;

  proto_kernel<<<dim3(DD / 256, TT, BB), 256, 0, stream>>>(patches, annos, protos);
  attn_kernel<<<dim3(CHUNKS, HEADS, BB), 256, 0, stream>>>(sk, protos, track_h);
  post_kernel<<<BB, 256, 0, stream>>>(track_h, out);
}